// Round 3
// baseline (150.779 us; speedup 1.0000x reference)
//
#include <hip/hip_runtime.h>
#include <math.h>

#define B_ROWS 8192
#define DIM 64
#define NCODES 2048
#define NSPLIT 16                          // code-range splits for dist kernel
#define CODES_PER_SPLIT (NCODES / NSPLIT)  // 128
#define TILES_PER_WAVE (CODES_PER_SPLIT / 16) // 8 tiles of 16 codes
#define EPSF 1e-6f
#define BETA 0.25f
#define V_VAL 0.125f                       // 1/sqrt(64)

typedef __attribute__((ext_vector_type(8))) short sh8;    // 8 bf16 = 4 VGPR
typedef __attribute__((ext_vector_type(4))) float f32x4;  // MFMA acc

__device__ __forceinline__ float wave_sum64(float v) {
#pragma unroll
    for (int m = 32; m >= 1; m >>= 1) v += __shfl_xor(v, m, 64);
    return v;
}

// RNE float -> bf16 bit trick (inputs finite)
__device__ __forceinline__ unsigned short f2bf(float f) {
    unsigned u = __float_as_uint(f);
    unsigned r = (u + 0x7fffu + ((u >> 16) & 1u)) >> 16;
    return (unsigned short)r;
}
__device__ __forceinline__ float bf2f(unsigned short h) {
    return __uint_as_float(((unsigned)h) << 16);
}

// Fragment address helper: frag #((tile16*3 + split)*2 + khalf) is 64 lanes x 16B,
// element (lane, j) = split_s(src[tile16*16 + (lane&15)][khalf*32 + (lane>>4)*8 + j]).
// Writer side: given (row_or_code rc, dim): tile=rc>>4, m=rc&15, h=dim>>5,
// q=(dim>>3)&3, j=dim&7, lane'=q*16+m.

// Kernel 1 (fused prep) — BIT-IDENTICAL to round 2 (control for the A/B).
__global__ void rq_prep(const float* __restrict__ x,
                        const float* __restrict__ pq,
                        const float* __restrict__ codes,
                        float* __restrict__ cn,
                        unsigned short* __restrict__ cfrag,
                        unsigned short* __restrict__ xfrag,
                        float* __restrict__ uo,
                        float* __restrict__ duv,
                        unsigned long long* __restrict__ keys) {
    int tid = threadIdx.x;
    int lane = tid & 63;                 // dim
    int bid = blockIdx.x;

    if (bid < B_ROWS / 4) {
        int r = bid * 4 + (tid >> 6);    // row
        float xv = x[(size_t)r * DIM + lane];
        float qv = pq[(size_t)r * DIM + lane];
        float n2 = wave_sum64(qv * qv);
        float inv = 1.0f / fmaxf(sqrtf(n2), EPSF);
        float uv = qv * inv;
        float d = V_VAL * wave_sum64(uv);
        float a = wave_sum64(uv * xv);
        float b = V_VAL * wave_sum64(xv);
        float den = 1.0f + d + EPSF;
        float cu = -b + (d * b - a) / den;
        float cv = a - (b - d * a) / den;
        float xcv = xv + uv * cu + V_VAL * cv;

        uo[(size_t)r * DIM + lane] = uv;
        if (lane == 0) duv[r] = d;
        if (lane == 1) keys[r] = 0xFFFFFFFFFFFFFFFFull;  // argmin identity

        unsigned short s0 = f2bf(xcv);
        float rr = xcv - bf2f(s0);
        unsigned short s1 = f2bf(rr);
        rr -= bf2f(s1);
        unsigned short s2 = f2bf(rr);

        int rt = r >> 4, m = r & 15;
        int h = lane >> 5, q = (lane >> 3) & 3, j = lane & 7;
        int lanep = q * 16 + m;
        size_t base = ((size_t)(rt * 3) * 2 + h) * 512 + (size_t)lanep * 8 + j;
        xfrag[base] = s0;
        xfrag[base + 2 * 512] = s1;
        xfrag[base + 4 * 512] = s2;
    } else {
        int c = (bid - B_ROWS / 4) * 4 + (tid >> 6); // code
        float cvv = codes[(size_t)c * DIM + lane];
        float s = wave_sum64(cvv * cvv);
        if (lane == 0) cn[c] = s;

        unsigned short s0 = f2bf(cvv);
        float rr = cvv - bf2f(s0);
        unsigned short s1 = f2bf(rr);
        rr -= bf2f(s1);
        unsigned short s2 = f2bf(rr);

        int ct = c >> 4, m = c & 15;
        int h = lane >> 5, q = (lane >> 3) & 3, j = lane & 7;
        int lanep = q * 16 + m;
        size_t base = ((size_t)(ct * 3) * 2 + h) * 512 + (size_t)lanep * 8 + j;
        cfrag[base] = s0;
        cfrag[base + 2 * 512] = s1;
        cfrag[base + 4 * 512] = s2;
    }
}

// Kernel 2: MFMA distance scan — EXPERIMENT KERNEL.
// Change A (chain-split): h=0 / h=1 accumulate into independent accA/accB
// (8 interleaved dependent chains of depth 6 per wave instead of 4 chains
// of depth 12) -> 16 chains/SIMD at 2 waves/SIMD, 2x dependent-latency
// slack over the issue pipe. Score uses accA+accB.
// Change B (self-amplification probe): rep=2 loop around the tile scan.
// Idempotent: identical scores, min-of-same, atomicMin of same keys.
// Makes dist's true cost readable in the top-5 dispatch table (if dist is
// the ~25 us suspect, its dispatch now shows at ~50 us > the 43 us fills).
__global__ __launch_bounds__(256, 2) void rq_dist_mfma(
        const unsigned short* __restrict__ xfrag,
        const unsigned short* __restrict__ cfrag,
        const float* __restrict__ cn,
        unsigned long long* __restrict__ keys) {
    int tid = threadIdx.x;
    int lane = tid & 63;
    int w = tid >> 6;
    int rb = blockIdx.x >> 4;     // 32 row-blocks of 256 rows
    int cs = blockIdx.x & (NSPLIT - 1);
    int r0 = rb * 256 + w * 64;
    int rt0 = r0 >> 4;

    const sh8* xf = (const sh8*)xfrag;
    const sh8* cf = (const sh8*)cfrag;

    sh8 afr[4][3][2];
#pragma unroll
    for (int rs = 0; rs < 4; ++rs)
#pragma unroll
        for (int s = 0; s < 3; ++s)
#pragma unroll
            for (int h = 0; h < 2; ++h)
                afr[rs][s][h] = xf[(size_t)(((rt0 + rs) * 3 + s) * 2 + h) * 64 + lane];

    int cbase = cs * CODES_PER_SPLIT;
    float cnv[TILES_PER_WAVE];
    {
        int c_l = cbase + (lane & 15);
#pragma unroll
        for (int t = 0; t < TILES_PER_WAVE; ++t) cnv[t] = cn[c_l + t * 16];
    }

    float bv[4][4];
    int bi[4][4];
#pragma unroll
    for (int rs = 0; rs < 4; ++rs)
#pragma unroll
        for (int i = 0; i < 4; ++i) { bv[rs][i] = INFINITY; bi[rs][i] = 0x7fffffff; }

    auto loadB = [&](sh8 (&Bf)[3][2], int t) {
        int ct = (cbase + t * 16) >> 4;
#pragma unroll
        for (int s = 0; s < 3; ++s)
#pragma unroll
            for (int h = 0; h < 2; ++h)
                Bf[s][h] = cf[(size_t)((ct * 3 + s) * 2 + h) * 64 + lane];
    };

    auto computeTile = [&](const sh8 (&Bf)[3][2], int t) {
        f32x4 accA[4], accB[4];
#pragma unroll
        for (int rs = 0; rs < 4; ++rs) {
            accA[rs] = (f32x4){0.f, 0.f, 0.f, 0.f};
            accB[rs] = (f32x4){0.f, 0.f, 0.f, 0.f};
        }
        // 8 independent chains of depth 6 (4 rowsets x 2 K-halves),
        // smallest-weight products first within each chain.
#pragma unroll
        for (int rs = 0; rs < 4; ++rs) {
            accA[rs] = __builtin_amdgcn_mfma_f32_16x16x32_bf16(afr[rs][2][0], Bf[0][0], accA[rs], 0, 0, 0);
            accB[rs] = __builtin_amdgcn_mfma_f32_16x16x32_bf16(afr[rs][2][1], Bf[0][1], accB[rs], 0, 0, 0);
            accA[rs] = __builtin_amdgcn_mfma_f32_16x16x32_bf16(afr[rs][1][0], Bf[1][0], accA[rs], 0, 0, 0);
            accB[rs] = __builtin_amdgcn_mfma_f32_16x16x32_bf16(afr[rs][1][1], Bf[1][1], accB[rs], 0, 0, 0);
            accA[rs] = __builtin_amdgcn_mfma_f32_16x16x32_bf16(afr[rs][0][0], Bf[2][0], accA[rs], 0, 0, 0);
            accB[rs] = __builtin_amdgcn_mfma_f32_16x16x32_bf16(afr[rs][0][1], Bf[2][1], accB[rs], 0, 0, 0);
            accA[rs] = __builtin_amdgcn_mfma_f32_16x16x32_bf16(afr[rs][1][0], Bf[0][0], accA[rs], 0, 0, 0);
            accB[rs] = __builtin_amdgcn_mfma_f32_16x16x32_bf16(afr[rs][1][1], Bf[0][1], accB[rs], 0, 0, 0);
            accA[rs] = __builtin_amdgcn_mfma_f32_16x16x32_bf16(afr[rs][0][0], Bf[1][0], accA[rs], 0, 0, 0);
            accB[rs] = __builtin_amdgcn_mfma_f32_16x16x32_bf16(afr[rs][0][1], Bf[1][1], accB[rs], 0, 0, 0);
            accA[rs] = __builtin_amdgcn_mfma_f32_16x16x32_bf16(afr[rs][0][0], Bf[0][0], accA[rs], 0, 0, 0);
            accB[rs] = __builtin_amdgcn_mfma_f32_16x16x32_bf16(afr[rs][0][1], Bf[0][1], accB[rs], 0, 0, 0);
        }
        int idxv = cbase + t * 16 + (lane & 15);
        float cv = cnv[t];
#pragma unroll
        for (int rs = 0; rs < 4; ++rs)
#pragma unroll
            for (int reg = 0; reg < 4; ++reg) {
                float sc = fmaf(-2.0f, accA[rs][reg] + accB[rs][reg], cv);
                if (sc < bv[rs][reg]) { bv[rs][reg] = sc; bi[rs][reg] = idxv; }
            }
    };

#pragma unroll 1
    for (int rep = 0; rep < 2; ++rep) {
        // prevent cross-rep CSE of the B-frag loads / score math
        asm volatile("" ::: "memory");
        sh8 bufA[3][2], bufB[3][2];
        loadB(bufA, 0);
#pragma unroll
        for (int tt = 0; tt < TILES_PER_WAVE / 2; ++tt) {
            loadB(bufB, 2 * tt + 1);
            computeTile(bufA, 2 * tt);
            if (tt < TILES_PER_WAVE / 2 - 1) loadB(bufA, 2 * tt + 2);
            computeTile(bufB, 2 * tt + 1);
        }
    }

    // Per-row reduction across the 16 cols (lane bits 0-3), lexicographic
    // (val, idx) -> first-occurrence semantics. row = r0 + rs*16 + (lane>>4)*4 + reg.
#pragma unroll
    for (int rs = 0; rs < 4; ++rs) {
#pragma unroll
        for (int reg = 0; reg < 4; ++reg) {
            float v = bv[rs][reg];
            int ix = bi[rs][reg];
#pragma unroll
            for (int m = 1; m < 16; m <<= 1) {
                float ov = __shfl_xor(v, m, 64);
                int oi = __shfl_xor(ix, m, 64);
                if (ov < v || (ov == v && oi < ix)) { v = ov; ix = oi; }
            }
            if ((lane & 15) == reg) {
                int row = r0 + rs * 16 + (lane >> 4) * 4 + reg;
                unsigned u = __float_as_uint(v);
                unsigned k32 = (u & 0x80000000u) ? ~u : (u | 0x80000000u);
                unsigned long long key =
                    ((unsigned long long)k32 << 32) | (unsigned long long)(unsigned)ix;
                atomicMin(&keys[row], key);
            }
        }
    }
}

// Kernel 3: thin epilogue — BIT-IDENTICAL to round 2.
__global__ void rq_epilogue(const float* __restrict__ x,
                            const float* __restrict__ codes,
                            const float* __restrict__ uo,
                            const float* __restrict__ duv,
                            const unsigned long long* __restrict__ keys,
                            float* __restrict__ out_q,
                            float* __restrict__ out_idx,
                            float* __restrict__ lossbuf) {
    int tid = threadIdx.x;
    int lane = tid & 63;
    int r = blockIdx.x * 4 + (tid >> 6);

    int idx = (int)(unsigned)(keys[r] & 0xFFFFFFFFull);

    float qc = codes[(size_t)idx * DIM + lane];
    float uv = uo[(size_t)r * DIM + lane];
    float xv = x[(size_t)r * DIM + lane];
    float d = duv[r];

    float aq = wave_sum64(uv * qc);
    float bq = V_VAL * wave_sum64(qc);
    float den = 1.0f + d + EPSF;
    float cu = bq + (d * bq - aq) / den;
    float cv = -aq - (bq - d * aq) / den;
    float qout = qc + uv * cu + V_VAL * cv;
    out_q[(size_t)r * DIM + lane] = qout;

    float diff = xv - qc;
    float l = wave_sum64(diff * diff);
    if (lane == 0) {
        out_idx[r] = (float)idx;
        lossbuf[r] = l;
    }
}

// Kernel 4: single-block loss reduce — BIT-IDENTICAL to round 2.
__global__ void rq_loss_reduce(const float* __restrict__ lossbuf,
                               float* __restrict__ out_loss) {
    __shared__ float part[16];
    int tid = threadIdx.x;  // 1024 threads
    float s = 0.f;
#pragma unroll
    for (int i = 0; i < B_ROWS / 1024; ++i) s += lossbuf[tid + i * 1024];
    s = wave_sum64(s);
    if ((tid & 63) == 0) part[tid >> 6] = s;
    __syncthreads();
    if (tid < 64) {
        float v = (tid < 16) ? part[tid] : 0.f;
        v = wave_sum64(v);
        if (tid == 0) *out_loss = v * (1.0f + BETA) * (1.0f / (float)B_ROWS);
    }
}

extern "C" void kernel_launch(void* const* d_in, const int* in_sizes, int n_in,
                              void* d_out, int out_size, void* d_ws, size_t ws_size,
                              hipStream_t stream) {
    const float* x     = (const float*)d_in[0];
    const float* pq    = (const float*)d_in[1];
    const float* codes = (const float*)d_in[2];

    float* out      = (float*)d_out;
    float* out_q    = out;                         // B*D
    float* out_idx  = out + (size_t)B_ROWS * DIM;  // B
    float* out_loss = out_idx + B_ROWS;            // 1

    char* ws = (char*)d_ws;
    const size_t MB = 1024 * 1024;
    float* uo                = (float*)ws;                            // 2 MB
    float* duv               = (float*)(ws + 2 * MB);                 // 32 KB
    float* cn                = (float*)(ws + 2 * MB + 32 * 1024);     // 8 KB
    unsigned long long* keys = (unsigned long long*)(ws + 2 * MB + 64 * 1024); // 64 KB
    float* lbuf              = (float*)(ws + 2 * MB + 128 * 1024);    // 32 KB
    unsigned short* xfrg     = (unsigned short*)(ws + 3 * MB);        // 3 MB
    unsigned short* cfrg     = (unsigned short*)(ws + 6 * MB);        // 768 KB

    rq_prep<<<B_ROWS / 4 + NCODES / 4, 256, 0, stream>>>(
        x, pq, codes, cn, cfrg, xfrg, uo, duv, keys);
    rq_dist_mfma<<<32 * NSPLIT, 256, 0, stream>>>(xfrg, cfrg, cn, keys);
    rq_epilogue<<<B_ROWS / 4, 256, 0, stream>>>(
        x, codes, uo, duv, keys, out_q, out_idx, lbuf);
    rq_loss_reduce<<<1, 1024, 0, stream>>>(lbuf, out_loss);
}

// Round 4
// 89.751 us; speedup vs baseline: 1.6800x; 1.6800x over previous
//
#include <hip/hip_runtime.h>
#include <math.h>

#define B_ROWS 8192
#define DIM 64
#define NCODES 2048
#define NSPLIT 16                          // code-range splits for dist kernel
#define CODES_PER_SPLIT (NCODES / NSPLIT)  // 128
#define TILES_PER_WAVE (CODES_PER_SPLIT / 16) // 8 tiles of 16 codes
#define EPSF 1e-6f
#define BETA 0.25f
#define V_VAL 0.125f                       // 1/sqrt(64)

typedef __attribute__((ext_vector_type(8))) short sh8;    // 8 bf16 = 4 VGPR
typedef __attribute__((ext_vector_type(4))) float f32x4;  // MFMA acc

__device__ __forceinline__ float wave_sum64(float v) {
#pragma unroll
    for (int m = 32; m >= 1; m >>= 1) v += __shfl_xor(v, m, 64);
    return v;
}

// RNE float -> bf16 bit trick (inputs finite)
__device__ __forceinline__ unsigned short f2bf(float f) {
    unsigned u = __float_as_uint(f);
    unsigned r = (u + 0x7fffu + ((u >> 16) & 1u)) >> 16;
    return (unsigned short)r;
}
__device__ __forceinline__ float bf2f(unsigned short h) {
    return __uint_as_float(((unsigned)h) << 16);
}

// Fragment address helper: frag #((tile16*3 + split)*2 + khalf) is 64 lanes x 16B,
// element (lane, j) = split_s(src[tile16*16 + (lane&15)][khalf*32 + (lane>>4)*8 + j]).
// Writer side: given (row_or_code rc, dim): tile=rc>>4, m=rc&15, h=dim>>5,
// q=(dim>>3)&3, j=dim&7, lane'=q*16+m.

// Kernel 1 (fused prep) — BIT-IDENTICAL to rounds 2/3 (control).
__global__ void rq_prep(const float* __restrict__ x,
                        const float* __restrict__ pq,
                        const float* __restrict__ codes,
                        float* __restrict__ cn,
                        unsigned short* __restrict__ cfrag,
                        unsigned short* __restrict__ xfrag,
                        float* __restrict__ uo,
                        float* __restrict__ duv,
                        unsigned long long* __restrict__ keys) {
    int tid = threadIdx.x;
    int lane = tid & 63;                 // dim
    int bid = blockIdx.x;

    if (bid < B_ROWS / 4) {
        int r = bid * 4 + (tid >> 6);    // row
        float xv = x[(size_t)r * DIM + lane];
        float qv = pq[(size_t)r * DIM + lane];
        float n2 = wave_sum64(qv * qv);
        float inv = 1.0f / fmaxf(sqrtf(n2), EPSF);
        float uv = qv * inv;
        float d = V_VAL * wave_sum64(uv);
        float a = wave_sum64(uv * xv);
        float b = V_VAL * wave_sum64(xv);
        float den = 1.0f + d + EPSF;
        float cu = -b + (d * b - a) / den;
        float cv = a - (b - d * a) / den;
        float xcv = xv + uv * cu + V_VAL * cv;

        uo[(size_t)r * DIM + lane] = uv;
        if (lane == 0) duv[r] = d;
        if (lane == 1) keys[r] = 0xFFFFFFFFFFFFFFFFull;  // argmin identity

        unsigned short s0 = f2bf(xcv);
        float rr = xcv - bf2f(s0);
        unsigned short s1 = f2bf(rr);
        rr -= bf2f(s1);
        unsigned short s2 = f2bf(rr);

        int rt = r >> 4, m = r & 15;
        int h = lane >> 5, q = (lane >> 3) & 3, j = lane & 7;
        int lanep = q * 16 + m;
        size_t base = ((size_t)(rt * 3) * 2 + h) * 512 + (size_t)lanep * 8 + j;
        xfrag[base] = s0;
        xfrag[base + 2 * 512] = s1;
        xfrag[base + 4 * 512] = s2;
    } else {
        int c = (bid - B_ROWS / 4) * 4 + (tid >> 6); // code
        float cvv = codes[(size_t)c * DIM + lane];
        float s = wave_sum64(cvv * cvv);
        if (lane == 0) cn[c] = s;

        unsigned short s0 = f2bf(cvv);
        float rr = cvv - bf2f(s0);
        unsigned short s1 = f2bf(rr);
        rr -= bf2f(s1);
        unsigned short s2 = f2bf(rr);

        int ct = c >> 4, m = c & 15;
        int h = lane >> 5, q = (lane >> 3) & 3, j = lane & 7;
        int lanep = q * 16 + m;
        size_t base = ((size_t)(ct * 3) * 2 + h) * 512 + (size_t)lanep * 8 + j;
        cfrag[base] = s0;
        cfrag[base + 2 * 512] = s1;
        cfrag[base + 4 * 512] = s2;
    }
}

// Kernel 2: MFMA distance scan — REGISTER-SLIM rewrite (round-3 lesson:
// the 64-row / double-buffered / chain-split versions had ~200-220 live
// VGPRs vs 128 allocated -> per-tile accumulator spill/fill = 121 MB
// FETCH + 187 MB WRITE of scratch traffic per dispatch, MfmaUtil 11%).
// This version budgets ~112 live VGPRs so NOTHING spills:
//   afr 12xsh8=48, bfr 6xsh8=24 (single buffer), acc 2xf32x4=8,
//   bv/bi 16, cnv 8, addressing ~8.
// Latency hiding comes from TLP: 1024 blocks = 4096 waves = 4 waves/SIMD
// at <=128 VGPR (16 waves/CU), each wave an independent load->MFMA stream.
// #pragma unroll 1 on the tile loop keeps pressure flat. Scores/tie-break
// bit-identical to rounds 0/2 (same MFMA accumulation order per acc).
__global__ __launch_bounds__(256) void rq_dist_mfma(
        const unsigned short* __restrict__ xfrag,
        const unsigned short* __restrict__ cfrag,
        const float* __restrict__ cn,
        unsigned long long* __restrict__ keys) {
    int tid = threadIdx.x;
    int lane = tid & 63;
    int w = tid >> 6;
    int rb = blockIdx.x >> 4;     // 64 row-blocks of 128 rows
    int cs = blockIdx.x & (NSPLIT - 1);
    int r0 = rb * 128 + w * 32;
    int rt0 = r0 >> 4;

    const sh8* xf = (const sh8*)xfrag;
    const sh8* cf = (const sh8*)cfrag;

    sh8 afr[2][3][2];
#pragma unroll
    for (int rs = 0; rs < 2; ++rs)
#pragma unroll
        for (int s = 0; s < 3; ++s)
#pragma unroll
            for (int h = 0; h < 2; ++h)
                afr[rs][s][h] = xf[(size_t)(((rt0 + rs) * 3 + s) * 2 + h) * 64 + lane];

    int cbase = cs * CODES_PER_SPLIT;
    float cnv[TILES_PER_WAVE];
    {
        int c_l = cbase + (lane & 15);
#pragma unroll
        for (int t = 0; t < TILES_PER_WAVE; ++t) cnv[t] = cn[c_l + t * 16];
    }

    float bv0[4], bv1[4];
    int bi0[4], bi1[4];
#pragma unroll
    for (int i = 0; i < 4; ++i) {
        bv0[i] = INFINITY; bv1[i] = INFINITY;
        bi0[i] = 0x7fffffff; bi1[i] = 0x7fffffff;
    }

#pragma unroll 1
    for (int t = 0; t < TILES_PER_WAVE; ++t) {
        int c0 = cbase + t * 16;
        int ct = c0 >> 4;
        sh8 bfr[3][2];
#pragma unroll
        for (int s = 0; s < 3; ++s)
#pragma unroll
            for (int h = 0; h < 2; ++h)
                bfr[s][h] = cf[(size_t)((ct * 3 + s) * 2 + h) * 64 + lane];

        f32x4 acc0 = {0.f, 0.f, 0.f, 0.f};
        f32x4 acc1 = {0.f, 0.f, 0.f, 0.f};
#pragma unroll
        for (int h = 0; h < 2; ++h) {
            // smallest-weight terms first: (2,0),(1,1),(0,2) then (1,0),(0,1),(0,0)
            acc0 = __builtin_amdgcn_mfma_f32_16x16x32_bf16(afr[0][2][h], bfr[0][h], acc0, 0, 0, 0);
            acc0 = __builtin_amdgcn_mfma_f32_16x16x32_bf16(afr[0][1][h], bfr[1][h], acc0, 0, 0, 0);
            acc0 = __builtin_amdgcn_mfma_f32_16x16x32_bf16(afr[0][0][h], bfr[2][h], acc0, 0, 0, 0);
            acc0 = __builtin_amdgcn_mfma_f32_16x16x32_bf16(afr[0][1][h], bfr[0][h], acc0, 0, 0, 0);
            acc0 = __builtin_amdgcn_mfma_f32_16x16x32_bf16(afr[0][0][h], bfr[1][h], acc0, 0, 0, 0);
            acc0 = __builtin_amdgcn_mfma_f32_16x16x32_bf16(afr[0][0][h], bfr[0][h], acc0, 0, 0, 0);

            acc1 = __builtin_amdgcn_mfma_f32_16x16x32_bf16(afr[1][2][h], bfr[0][h], acc1, 0, 0, 0);
            acc1 = __builtin_amdgcn_mfma_f32_16x16x32_bf16(afr[1][1][h], bfr[1][h], acc1, 0, 0, 0);
            acc1 = __builtin_amdgcn_mfma_f32_16x16x32_bf16(afr[1][0][h], bfr[2][h], acc1, 0, 0, 0);
            acc1 = __builtin_amdgcn_mfma_f32_16x16x32_bf16(afr[1][1][h], bfr[0][h], acc1, 0, 0, 0);
            acc1 = __builtin_amdgcn_mfma_f32_16x16x32_bf16(afr[1][0][h], bfr[1][h], acc1, 0, 0, 0);
            acc1 = __builtin_amdgcn_mfma_f32_16x16x32_bf16(afr[1][0][h], bfr[0][h], acc1, 0, 0, 0);
        }

        float cnvt = cnv[t];
        int idxv = c0 + (lane & 15);
#pragma unroll
        for (int reg = 0; reg < 4; ++reg) {
            float s0 = fmaf(-2.0f, acc0[reg], cnvt);
            if (s0 < bv0[reg]) { bv0[reg] = s0; bi0[reg] = idxv; }
            float s1 = fmaf(-2.0f, acc1[reg], cnvt);
            if (s1 < bv1[reg]) { bv1[reg] = s1; bi1[reg] = idxv; }
        }
    }

    // Per-row reduction across the 16 cols (lane bits 0-3), lexicographic
    // (val, idx) -> first-occurrence semantics. row = r0 + rs*16 + (lane>>4)*4 + reg.
#pragma unroll
    for (int rs = 0; rs < 2; ++rs) {
#pragma unroll
        for (int reg = 0; reg < 4; ++reg) {
            float v = rs ? bv1[reg] : bv0[reg];
            int ix = rs ? bi1[reg] : bi0[reg];
#pragma unroll
            for (int m = 1; m < 16; m <<= 1) {
                float ov = __shfl_xor(v, m, 64);
                int oi = __shfl_xor(ix, m, 64);
                if (ov < v || (ov == v && oi < ix)) { v = ov; ix = oi; }
            }
            if ((lane & 15) == reg) {
                int row = r0 + rs * 16 + (lane >> 4) * 4 + reg;
                unsigned u = __float_as_uint(v);
                unsigned k32 = (u & 0x80000000u) ? ~u : (u | 0x80000000u);
                unsigned long long key =
                    ((unsigned long long)k32 << 32) | (unsigned long long)(unsigned)ix;
                atomicMin(&keys[row], key);
            }
        }
    }
}

// Kernel 3: thin epilogue — BIT-IDENTICAL to round 2.
__global__ void rq_epilogue(const float* __restrict__ x,
                            const float* __restrict__ codes,
                            const float* __restrict__ uo,
                            const float* __restrict__ duv,
                            const unsigned long long* __restrict__ keys,
                            float* __restrict__ out_q,
                            float* __restrict__ out_idx,
                            float* __restrict__ lossbuf) {
    int tid = threadIdx.x;
    int lane = tid & 63;
    int r = blockIdx.x * 4 + (tid >> 6);

    int idx = (int)(unsigned)(keys[r] & 0xFFFFFFFFull);

    float qc = codes[(size_t)idx * DIM + lane];
    float uv = uo[(size_t)r * DIM + lane];
    float xv = x[(size_t)r * DIM + lane];
    float d = duv[r];

    float aq = wave_sum64(uv * qc);
    float bq = V_VAL * wave_sum64(qc);
    float den = 1.0f + d + EPSF;
    float cu = bq + (d * bq - aq) / den;
    float cv = -aq - (bq - d * aq) / den;
    float qout = qc + uv * cu + V_VAL * cv;
    out_q[(size_t)r * DIM + lane] = qout;

    float diff = xv - qc;
    float l = wave_sum64(diff * diff);
    if (lane == 0) {
        out_idx[r] = (float)idx;
        lossbuf[r] = l;
    }
}

// Kernel 4: single-block loss reduce — BIT-IDENTICAL to round 2.
__global__ void rq_loss_reduce(const float* __restrict__ lossbuf,
                               float* __restrict__ out_loss) {
    __shared__ float part[16];
    int tid = threadIdx.x;  // 1024 threads
    float s = 0.f;
#pragma unroll
    for (int i = 0; i < B_ROWS / 1024; ++i) s += lossbuf[tid + i * 1024];
    s = wave_sum64(s);
    if ((tid & 63) == 0) part[tid >> 6] = s;
    __syncthreads();
    if (tid < 64) {
        float v = (tid < 16) ? part[tid] : 0.f;
        v = wave_sum64(v);
        if (tid == 0) *out_loss = v * (1.0f + BETA) * (1.0f / (float)B_ROWS);
    }
}

extern "C" void kernel_launch(void* const* d_in, const int* in_sizes, int n_in,
                              void* d_out, int out_size, void* d_ws, size_t ws_size,
                              hipStream_t stream) {
    const float* x     = (const float*)d_in[0];
    const float* pq    = (const float*)d_in[1];
    const float* codes = (const float*)d_in[2];

    float* out      = (float*)d_out;
    float* out_q    = out;                         // B*D
    float* out_idx  = out + (size_t)B_ROWS * DIM;  // B
    float* out_loss = out_idx + B_ROWS;            // 1

    char* ws = (char*)d_ws;
    const size_t MB = 1024 * 1024;
    float* uo                = (float*)ws;                            // 2 MB
    float* duv               = (float*)(ws + 2 * MB);                 // 32 KB
    float* cn                = (float*)(ws + 2 * MB + 32 * 1024);     // 8 KB
    unsigned long long* keys = (unsigned long long*)(ws + 2 * MB + 64 * 1024); // 64 KB
    float* lbuf              = (float*)(ws + 2 * MB + 128 * 1024);    // 32 KB
    unsigned short* xfrg     = (unsigned short*)(ws + 3 * MB);        // 3 MB
    unsigned short* cfrg     = (unsigned short*)(ws + 6 * MB);        // 768 KB

    rq_prep<<<B_ROWS / 4 + NCODES / 4, 256, 0, stream>>>(
        x, pq, codes, cn, cfrg, xfrg, uo, duv, keys);
    rq_dist_mfma<<<64 * NSPLIT, 256, 0, stream>>>(xfrg, cfrg, cn, keys);
    rq_epilogue<<<B_ROWS / 4, 256, 0, stream>>>(
        x, codes, uo, duv, keys, out_q, out_idx, lbuf);
    rq_loss_reduce<<<1, 1024, 0, stream>>>(lbuf, out_loss);
}